// Round 4
// baseline (11959.982 us; speedup 1.0000x reference)
//
#include <hip/hip_runtime.h>
#include <hip/hip_bf16.h>
#include <stdint.h>

// Problem constants (fixed by the reference).
#define T_DIM 8192
#define S_DIM 1024
#define B_DIM 8192

// ---------------------------------------------------------------------------
// R3 DIAGNOSTIC: single-kernel, ZERO-workspace brute force.
//   lam(i) = relu( mu[s] + beta * H[t] ),
//   H[t]   = sum_{tp<t} c[tp,s] * a^(t-tp),   c[tp,s] = sum_sp obs[tp,sp]*alpha[sp,s]
// computed per query via a per-lane Horner over tp on sp-slices (linearity:
// Horner and the sp-sum commute), then a block reduction. Shares NOTHING with
// the previous staged pipeline: no GEMM, no cgrid, no chunk/carry, no d_ws.
// One block per query, 256 threads; thread l owns sp in {l, l+256, l+512, l+768}.
__global__ __launch_bounds__(256) void brute_query_kernel(
        const int* __restrict__ tq, const int* __restrict__ sq,
        const int* __restrict__ obs,      // [T][S] int32
        const float* __restrict__ alpha,  // [S][S] f32, alpha[sp][s]
        const float* __restrict__ beta,   // [1]
        const float* __restrict__ mu,     // [S]
        float* __restrict__ out) {        // [B]
    const int i = blockIdx.x;
    const int t = tq[i];
    const int s = sq[i];
    const float b = beta[0];
    const float a = expf(-b);
    const int lane = threadIdx.x;

    // alpha column entries for this thread's sp-slice (contraction index = row)
    float al0 = alpha[(size_t)(lane +   0) * S_DIM + s];
    float al1 = alpha[(size_t)(lane + 256) * S_DIM + s];
    float al2 = alpha[(size_t)(lane + 512) * S_DIM + s];
    float al3 = alpha[(size_t)(lane + 768) * S_DIM + s];

    // Per-lane Horner: h_l = sum_{tp<t} part_l[tp] * a^(t-tp)
    float h = 0.f;
    for (int tp = 0; tp < t; ++tp) {
        const int* orow = obs + (size_t)tp * S_DIM;
        float part = (float)orow[lane +   0] * al0
                   + (float)orow[lane + 256] * al1
                   + (float)orow[lane + 512] * al2
                   + (float)orow[lane + 768] * al3;
        h = a * (h + part);
    }

    // Block reduction of h across 256 lanes.
    __shared__ float red[256];
    red[lane] = h;
    __syncthreads();
    for (int off = 128; off > 0; off >>= 1) {
        if (lane < off) red[lane] += red[lane + off];
        __syncthreads();
    }
    if (lane == 0) {
        float lam = mu[s] + b * red[0];
        out[i] = lam > 0.f ? lam : 0.f;
    }
}

// ---------------------------------------------------------------------------
extern "C" void kernel_launch(void* const* d_in, const int* in_sizes, int n_in,
                              void* d_out, int out_size, void* d_ws, size_t ws_size,
                              hipStream_t stream) {
    const int*   t     = (const int*)d_in[0];
    const int*   s     = (const int*)d_in[1];
    const int*   obs   = (const int*)d_in[2];
    const float* alpha = (const float*)d_in[3];
    const float* beta  = (const float*)d_in[4];
    const float* mu    = (const float*)d_in[5];
    float* out = (float*)d_out;

    (void)d_ws; (void)ws_size;  // deliberately unused this round

    brute_query_kernel<<<B_DIM, 256, 0, stream>>>(t, s, obs, alpha, beta, mu, out);
}

// Round 6
// 874.368 us; speedup vs baseline: 13.6784x; 13.6784x over previous
//
#include <hip/hip_runtime.h>
#include <hip/hip_bf16.h>
#include <stdint.h>

// Problem constants (fixed by the reference).
#define T_DIM 8192
#define S_DIM 1024
#define B_DIM 8192
#define CHUNK 64
#define NCHUNK 128
#define QCAP 2048   // per-chunk query cap; E[q/chunk]=64, 2048 is >100 sigma

// ---------------------------------------------------------------------------
// R5: SINGLE kernel, ZERO workspace (tests whether R1/R2/R4's shared failure
// came from multi-kernel + d_ws infrastructure, holding the chunk algorithm
// fixed). One block per chunk k (1024 threads, thread tid owns column sp=tid):
//   1) bucket this chunk's queries into LDS,
//   2) prefix: G[sp] = sum_{tp<64k} a^(64k-tp) * obs[tp][sp]  (register),
//   3) roll j=0..63: answer queries with t==64k+j via block dot
//      lam = relu(mu[s] + b * sum_sp G[sp]*alpha[sp][s]), then absorb row.
__global__ __launch_bounds__(1024) void chunk_all_kernel(
        const int* __restrict__ tq, const int* __restrict__ sq,
        const int* __restrict__ obs,      // [T][S] int32
        const float* __restrict__ alpha,  // [S][S] f32, alpha[sp][s]
        const float* __restrict__ beta,   // [1]
        const float* __restrict__ mu,     // [S]
        float* __restrict__ out) {        // [B]
    const int k   = blockIdx.x;
    const int tid = threadIdx.x;          // sp = tid
    const float b = beta[0];
    const float a = expf(-b);
    const int t0 = k << 6;

    __shared__ int   qkey[QCAP];          // (j<<13) | query index
    __shared__ int   qcnt_s;
    __shared__ float wred[16];

    if (tid == 0) qcnt_s = 0;
    __syncthreads();
    for (int i = tid; i < B_DIM; i += 1024) {
        int tv = tq[i];
        if ((tv >> 6) == k) {
            int p = atomicAdd(&qcnt_s, 1);
            if (p < QCAP) qkey[p] = ((tv - t0) << 13) | i;
        }
    }
    __syncthreads();
    int Q = qcnt_s; if (Q > QCAP) Q = QCAP;

    // 2) prefix over rows [0, t0): G = a*(G + obs[tp][tid]); t0 % 8 == 0.
    float G = 0.f;
    for (int tp = 0; tp < t0; tp += 8) {
        int o[8];
        #pragma unroll
        for (int r = 0; r < 8; ++r)
            o[r] = obs[(size_t)(tp + r) * S_DIM + tid];
        #pragma unroll
        for (int r = 0; r < 8; ++r)
            G = a * (G + (float)o[r]);
    }

    // 3) roll through the chunk.
    for (int j = 0; j < CHUNK; ++j) {
        // answer all queries with t == t0 + j (condition block-uniform)
        for (int q = 0; q < Q; ++q) {
            int key = qkey[q];
            if ((key >> 13) == j) {
                int i = key & 8191;
                int s = sq[i];
                float p = G * alpha[(size_t)tid * S_DIM + s];
                #pragma unroll
                for (int off = 32; off > 0; off >>= 1)
                    p += __shfl_down(p, off);
                if ((tid & 63) == 0) wred[tid >> 6] = p;
                __syncthreads();
                if (tid < 64) {                 // whole wave active for shfl
                    float v = (tid < 16) ? wred[tid] : 0.f;
                    v += __shfl_down(v, 8);
                    v += __shfl_down(v, 4);
                    v += __shfl_down(v, 2);
                    v += __shfl_down(v, 1);
                    if (tid == 0) {
                        float lam = mu[s] + b * v;
                        out[i] = lam > 0.f ? lam : 0.f;
                    }
                }
                __syncthreads();                // wred reusable
            }
        }
        // absorb row t0+j  ->  G becomes G[t0+j+1]
        int o = obs[(size_t)(t0 + j) * S_DIM + tid];
        G = a * (G + (float)o);
    }
}

// ---------------------------------------------------------------------------
extern "C" void kernel_launch(void* const* d_in, const int* in_sizes, int n_in,
                              void* d_out, int out_size, void* d_ws, size_t ws_size,
                              hipStream_t stream) {
    const int*   t     = (const int*)d_in[0];
    const int*   s     = (const int*)d_in[1];
    const int*   obs   = (const int*)d_in[2];
    const float* alpha = (const float*)d_in[3];
    const float* beta  = (const float*)d_in[4];
    const float* mu    = (const float*)d_in[5];
    float* out = (float*)d_out;

    (void)d_ws; (void)ws_size;  // deliberately unused: zero-workspace round

    chunk_all_kernel<<<NCHUNK, 1024, 0, stream>>>(t, s, obs, alpha, beta, mu, out);
}

// Round 7
// 223.888 us; speedup vs baseline: 53.4196x; 3.9054x over previous
//
#include <hip/hip_runtime.h>
#include <hip/hip_bf16.h>
#include <stdint.h>

// Problem constants (fixed by the reference).
#define T_DIM 8192
#define S_DIM 1024
#define B_DIM 8192
#define CHUNK 64
#define NCHUNK 128
#define QCAP 1024    // per-chunk query cap; E=64, sigma=8 -> 1024 is absurd margin

// Workspace layout (4.72 MB; R4 proved ws_size >= 9.44 MB)
#define OFF_ALPHAT 0u         // 4 MB  f32 [S][S]  alphaT[s][sp]
#define OFF_W      4194304u   // 512KB f32 [NCHUNK][S]
#define OFF_CNT    4718592u   // 64 B  barrier counter (memset to 0 on stream)
#define WS_NEEDED  4718656u

// ---------------------------------------------------------------------------
// R6: single dispatch, 3 phases separated by an in-kernel grid barrier.
//  pre :  bucket+sort queries (LDS); transpose 8 alpha cols -> alphaT (ws);
//         W[k] = 64-row chunk Horner (ws).
//  bar :  release(threadfence + agent atomicAdd) / acquire(spin + fence).
//         128 blocks x 1024 thr <= capacity of 256 CUs -> co-resident.
//  post:  U_k = scan of W[0..k); roll G through 64 rows answering queries
//         (16 waves fan out over the j-sorted list; coalesced alphaT dot).
__global__ __launch_bounds__(1024) void hawkes_fused_kernel(
        const int* __restrict__ tq, const int* __restrict__ sq,
        const int* __restrict__ obs,      // [T][S] int32
        const float* __restrict__ alpha,  // [S][S] f32, alpha[sp][s]
        const float* __restrict__ beta, const float* __restrict__ mu,
        float* __restrict__ alphaT,       // ws
        float* __restrict__ W,            // ws
        int* __restrict__ cnt,            // ws, pre-zeroed
        float* __restrict__ out) {
    const int k   = blockIdx.x;
    const int tid = threadIdx.x;          // sp = tid
    const int wv  = tid >> 6, lane = tid & 63;
    const float b = beta[0];
    const float a = expf(-b);
    const int t0 = k << 6;

    __shared__ int   qtmp[QCAP];
    __shared__ int   qkey[QCAP];          // sorted by j; (j<<13)|i
    __shared__ int   jcnt[CHUNK];
    __shared__ int   jstart[CHUNK + 1];
    __shared__ int   qcnt_s;
    __shared__ float Gs[S_DIM];

    if (tid == 0) qcnt_s = 0;
    if (tid < CHUNK) jcnt[tid] = 0;
    __syncthreads();

    // ---- bucket this chunk's queries ----
    for (int i = tid; i < B_DIM; i += 1024) {
        int tv = tq[i];
        if ((tv >> 6) == k) {
            int p = atomicAdd(&qcnt_s, 1);
            if (p < QCAP) {
                qtmp[p] = ((tv - t0) << 13) | i;
                atomicAdd(&jcnt[tv - t0], 1);
            }
        }
    }
    __syncthreads();
    int Q = qcnt_s < QCAP ? qcnt_s : QCAP;
    if (tid == 0) {                        // tiny serial prefix (64 bins)
        int acc = 0;
        for (int j = 0; j < CHUNK; ++j) { jstart[j] = acc; acc += jcnt[j]; }
        jstart[CHUNK] = acc;
    }
    __syncthreads();
    if (tid < CHUNK) jcnt[tid] = 0;        // reuse as scatter cursors
    __syncthreads();
    for (int p = tid; p < Q; p += 1024) {
        int key = qtmp[p], j = key >> 13;
        qkey[jstart[j] + atomicAdd(&jcnt[j], 1)] = key;
    }   // visibility of qkey covered by the grid barrier's __syncthreads

    // ---- phase 0: alphaT rows [8k, 8k+8) ----
    #pragma unroll
    for (int c = 0; c < 8; ++c) {
        int srow = 8 * k + c;
        alphaT[(size_t)srow * S_DIM + tid] = alpha[(size_t)tid * S_DIM + srow];
    }

    // ---- phase 1: W[k][sp] = fold of own 64 rows ----
    float acc = 0.f;
    for (int base = 0; base < CHUNK; base += 8) {
        int o[8];
        #pragma unroll
        for (int r = 0; r < 8; ++r)
            o[r] = obs[(size_t)(t0 + base + r) * S_DIM + tid];
        #pragma unroll
        for (int r = 0; r < 8; ++r)
            acc = a * (acc + (float)o[r]);
    }
    W[(size_t)k * S_DIM + tid] = acc;

    // ---- grid barrier (device scope; cross-XCD via agent fences) ----
    __syncthreads();                       // all waves' W/alphaT stores drained
    if (tid == 0) {
        __threadfence();                   // release: wbl2
        __hip_atomic_fetch_add(cnt, 1, __ATOMIC_RELEASE, __HIP_MEMORY_SCOPE_AGENT);
        int spins = 0;
        while (__hip_atomic_load(cnt, __ATOMIC_ACQUIRE, __HIP_MEMORY_SCOPE_AGENT)
               < NCHUNK) {
            __builtin_amdgcn_s_sleep(8);
            if (++spins > 4000000) break;  // ~0.9 s safety valve (loud failure)
        }
    }
    __syncthreads();
    __threadfence();                       // acquire: inv L1/L2 stale lines

    // ---- phase 2: U_k = scan of W[0..k) ----
    float aL = a;
    #pragma unroll
    for (int q = 0; q < 6; ++q) aL *= aL;  // a^64
    float G = 0.f;
    for (int kp = 0; kp < k; ++kp)
        G = aL * G + W[(size_t)kp * S_DIM + tid];

    // ---- phase 3: roll 64 rows, answering queries ----
    for (int j = 0; j < CHUNK; ++j) {
        Gs[tid] = G;
        __syncthreads();                   // Gs + (first iter) qkey visible
        // wave wv handles sorted matches jstart[j]+wv, +16, ...
        for (int q = jstart[j] + wv; q < jstart[j + 1]; q += 16) {
            int i = qkey[q] & 8191;
            int s = sq[i];
            const float* ar = alphaT + (size_t)s * S_DIM;
            float p = 0.f;
            #pragma unroll
            for (int c = 0; c < 16; ++c) { // col = lane + 64*c: LDS conflict-free,
                int col = lane + 64 * c;   // global coalesced
                p += Gs[col] * ar[col];
            }
            #pragma unroll
            for (int off = 32; off > 0; off >>= 1)
                p += __shfl_down(p, off);
            if (lane == 0) {
                float lam = mu[s] + b * p;
                out[i] = lam > 0.f ? lam : 0.f;
            }
        }
        __syncthreads();                   // queries done before Gs overwrite
        int o = obs[(size_t)(t0 + j) * S_DIM + tid];
        G = a * (G + (float)o);
    }
}

// ---------------------------------------------------------------------------
// Fallback: proven R5 single-kernel zero-ws version (874 us, absmax 0.0).
__global__ __launch_bounds__(1024) void chunk_all_kernel(
        const int* __restrict__ tq, const int* __restrict__ sq,
        const int* __restrict__ obs, const float* __restrict__ alpha,
        const float* __restrict__ beta, const float* __restrict__ mu,
        float* __restrict__ out) {
    const int k   = blockIdx.x;
    const int tid = threadIdx.x;
    const float b = beta[0];
    const float a = expf(-b);
    const int t0 = k << 6;
    __shared__ int   qkey[2048];
    __shared__ int   qcnt_s;
    __shared__ float wred[16];
    if (tid == 0) qcnt_s = 0;
    __syncthreads();
    for (int i = tid; i < B_DIM; i += 1024) {
        int tv = tq[i];
        if ((tv >> 6) == k) {
            int p = atomicAdd(&qcnt_s, 1);
            if (p < 2048) qkey[p] = ((tv - t0) << 13) | i;
        }
    }
    __syncthreads();
    int Q = qcnt_s; if (Q > 2048) Q = 2048;
    float G = 0.f;
    for (int tp = 0; tp < t0; tp += 8) {
        int o[8];
        #pragma unroll
        for (int r = 0; r < 8; ++r) o[r] = obs[(size_t)(tp + r) * S_DIM + tid];
        #pragma unroll
        for (int r = 0; r < 8; ++r) G = a * (G + (float)o[r]);
    }
    for (int j = 0; j < CHUNK; ++j) {
        for (int q = 0; q < Q; ++q) {
            int key = qkey[q];
            if ((key >> 13) == j) {
                int i = key & 8191;
                int s = sq[i];
                float p = G * alpha[(size_t)tid * S_DIM + s];
                #pragma unroll
                for (int off = 32; off > 0; off >>= 1) p += __shfl_down(p, off);
                if ((tid & 63) == 0) wred[tid >> 6] = p;
                __syncthreads();
                if (tid < 64) {
                    float v = (tid < 16) ? wred[tid] : 0.f;
                    v += __shfl_down(v, 8); v += __shfl_down(v, 4);
                    v += __shfl_down(v, 2); v += __shfl_down(v, 1);
                    if (tid == 0) {
                        float lam = mu[s] + b * v;
                        out[i] = lam > 0.f ? lam : 0.f;
                    }
                }
                __syncthreads();
            }
        }
        int o = obs[(size_t)(t0 + j) * S_DIM + tid];
        G = a * (G + (float)o);
    }
}

// ---------------------------------------------------------------------------
extern "C" void kernel_launch(void* const* d_in, const int* in_sizes, int n_in,
                              void* d_out, int out_size, void* d_ws, size_t ws_size,
                              hipStream_t stream) {
    const int*   t     = (const int*)d_in[0];
    const int*   s     = (const int*)d_in[1];
    const int*   obs   = (const int*)d_in[2];
    const float* alpha = (const float*)d_in[3];
    const float* beta  = (const float*)d_in[4];
    const float* mu    = (const float*)d_in[5];
    float* out = (float*)d_out;

    if (ws_size < (size_t)WS_NEEDED || d_ws == nullptr) {
        chunk_all_kernel<<<NCHUNK, 1024, 0, stream>>>(t, s, obs, alpha, beta, mu, out);
        return;
    }

    char* ws = (char*)d_ws;
    float* alphaT = (float*)(ws + OFF_ALPHAT);
    float* W      = (float*)(ws + OFF_W);
    int*   cnt    = (int*)  (ws + OFF_CNT);

    hipMemsetAsync(cnt, 0, 64, stream);   // barrier counter init (stream-ordered)
    hawkes_fused_kernel<<<NCHUNK, 1024, 0, stream>>>(
        t, s, obs, alpha, beta, mu, alphaT, W, cnt, out);
}